// Round 14
// baseline (70.609 us; speedup 1.0000x reference)
//
#include <hip/hip_runtime.h>
#include <math.h>

#define Bb 32
#define Tt 131072
#define SEG 4096              // emitted samples per block
#define LB 2048               // lookback samples (decay-sufficient, R12-validated)
#define REG (LB + SEG)        // merged region = 6144
#define NCB (Tt / SEG)        // 32 chunks per row -> grid 1024 (4 blocks/CU)
#define TPB 384               // 6 waves; threads 0..127 lookback, 128..383 emit
#define PT 16                 // REG / TPB
#define NW (TPB / 64)         // 6
#define ETH (LB / PT)         // 128 = first emit thread

// padded LDS index: +1 float per 16 -> inter-lane stride 17 (conflict-free)
#define PIDX(j) ((j) + ((j) >> 4))
#define XSP (PIDX(REG + 64) + 8)

__device__ __forceinline__ float sigmoidf_(float v) { return 1.0f / (1.0f + __expf(-v)); }
__device__ __forceinline__ float softplusf_(float z) {
  return fmaxf(z, 0.0f) + __logf(1.0f + __expf(-fabsf(z)));
}
__device__ __forceinline__ float dgainf_(float sa) {
  return fminf(1000.0f, __fdividef(1.0f, sqrtf(sa) + 1e-8f));
}
__device__ __forceinline__ float pow16f_(float r) {
  float r2 = r * r, r4 = r2 * r2, r8 = r4 * r4;
  return r8 * r8;
}

// NW-wave block scan of affine maps s -> m*s + b (thread order = time order).
// Exclusive prefix (Mex,Bex): state entering this thread = Mex*s0 + Bex.
template <int NWv>
__device__ __forceinline__ void affine_scan(
    float m, float b, float& Mex, float& Bex, float* smem) {
  const int lane = threadIdx.x & 63;
  const int wave = threadIdx.x >> 6;
  float mi = m, bi = b;
#pragma unroll
  for (int d = 1; d < 64; d <<= 1) {
    float mp = __shfl_up(mi, d);
    float bp = __shfl_up(bi, d);
    if (lane >= d) { bi = fmaf(mi, bp, bi); mi *= mp; }
  }
  __syncthreads();
  if (lane == 63) { smem[2 * wave] = mi; smem[2 * wave + 1] = bi; }
  __syncthreads();
  float Mw = 1.0f, Bw = 0.0f;
#pragma unroll
  for (int wv = 0; wv < NWv - 1; ++wv) {
    if (wv < wave) {
      float mw = smem[2 * wv], bw = smem[2 * wv + 1];
      Bw = fmaf(mw, Bw, bw);
      Mw = mw * Mw;
    }
  }
  float mep = __shfl_up(mi, 1);
  float bep = __shfl_up(bi, 1);
  float me = (lane == 0) ? 1.0f : mep;
  float be = (lane == 0) ? 0.0f : bep;
  Mex = me * Mw;
  Bex = fmaf(me, Bw, be);
}

// One channel over the merged region: stage raw x (zero-fill t<0), grab own x,
// 64-tap conv(x^2) with 16-wide group prefetch. Conv core identical to R12.
__device__ __forceinline__ void conv_region(
    const float* __restrict__ xr, const float* __restrict__ wc, const float cwc,
    float* xs, float (&xo)[PT], float (&pacc)[PT], const int t0, const int pb) {
  for (int i = threadIdx.x; i < (REG + 64) / 4; i += TPB) {
    const int g = t0 - 64 + 4 * i;   // raw lds[j] = x[t0-64+j]
    float4 v = make_float4(0.f, 0.f, 0.f, 0.f);
    if (g >= 0) v = *(const float4*)(xr + g);
    const int j = 4 * i;
    xs[j + 0 + ((j + 0) >> 4)] = v.x;
    xs[j + 1 + ((j + 1) >> 4)] = v.y;
    xs[j + 2 + ((j + 2) >> 4)] = v.z;
    xs[j + 3 + ((j + 3) >> 4)] = v.w;
  }
  __syncthreads();
#pragma unroll
  for (int i = 0; i < PT; ++i) xo[i] = xs[pb + 68 + i];   // own raw x
  float win[16];
#pragma unroll
  for (int i = 0; i < 16; ++i) {
    float u = xs[pb + 1 + i + ((1 + i) >> 4)];
    win[i] = u * u;
  }
#pragma unroll 1
  for (int g = 0; g < 4; ++g) {
    const int rb = pb + 17 * g + 18;   // padded addr of raw slot 16g+17
    float nxt[16];
#pragma unroll
    for (int j = 0; j < 16; ++j) {
      if (g * 16 + j < 63) {
        float u = xs[rb + j + ((j + 1) >> 4)];
        nxt[j] = u * u;
      }
    }
#pragma unroll
    for (int k2 = 0; k2 < 16; ++k2) {
      const float wk = wc[g * 16 + k2] * cwc;   // uniform -> scalar load
#pragma unroll
      for (int i = 0; i < PT; ++i)
        pacc[i] = fmaf(wk, win[(k2 + i) & 15], pacc[i]);
      win[k2] = nxt[k2];   // register move
    }
  }
}

// kA: merged-region kernel. Per block: conv+softplus over [tc-2048, tc+4096),
// ONE scan per EMA across the region (zero init == R12 lookback semantics;
// ch==0 exactness restored via thread-127 const-map override with p[b,0]).
// Emit threads (>=ETH) write gain + stats partials.
__global__ __launch_bounds__(TPB, 6) void k_gain(
    const float* __restrict__ x, const float* __restrict__ conv_w,
    const float* __restrict__ combine_w, const float* __restrict__ combine_b,
    const float* __restrict__ la_att, const float* __restrict__ la_rel,
    float* __restrict__ pg, float* __restrict__ partials) {
  __shared__ float xs[XSP];
  __shared__ float ssm[2 * NW];
  __shared__ float p0sh;
  __shared__ float red[NW][4];
  const int b = blockIdx.x / NCB;
  const int ch = blockIdx.x % NCB;
  const int tc = ch * SEG;
  const int t0 = tc - LB;               // region start
  const int tid = (int)threadIdx.x;
  const int pb = 17 * tid;
  const float a1 = sigmoidf_(la_att[0]); const float r1 = 1.0f - a1;
  const float a2 = sigmoidf_(la_rel[0]); const float r2 = 1.0f - a2;
  const float cb = combine_b[0];
  const float* xr0 = x + (size_t)(b * 2 + 0) * Tt;
  const float* xr1 = x + (size_t)(b * 2 + 1) * Tt;

  float pacc[PT];
#pragma unroll
  for (int i = 0; i < PT; ++i) pacc[i] = cb;
  float xa[PT], xb[PT];
  conv_region(xr0, conv_w, combine_w[0], xs, xa, pacc, t0, pb);
  __syncthreads();   // ch0 window reads done before ch1 staging overwrites
  conv_region(xr1, conv_w + 64, combine_w[1], xs, xb, pacc, t0, pb);
  float pv[PT];
#pragma unroll
  for (int i = 0; i < PT; ++i) pv[i] = softplusf_(pacc[i]) + 1e-8f;

  // publish p[b,0] (first emit element of ch==0 blocks) for the init override
  if (ch == 0 && tid == ETH) p0sh = pv[0];
  __syncthreads();
  const float p0 = p0sh;   // valid only when ch==0; unused otherwise

  // ---- EMA1 scan across the merged region
  float e1 = 0.0f;
#pragma unroll
  for (int i = 0; i < PT; ++i) e1 = fmaf(a1, pv[i], r1 * e1);
  float m1 = pow16f_(r1), b1 = e1;
  if (ch == 0 && tid == ETH - 1) { m1 = 0.0f; b1 = p0; }   // const map: exact init
  float Mex, Bex;
  affine_scan<NW>(m1, b1, Mex, Bex, ssm);
  float y = Bex;   // s0 = 0 (zero-init lookback); override handles ch==0
  float dg[PT];
  float e2 = 0.0f;
#pragma unroll
  for (int i = 0; i < PT; ++i) {
    y = fmaf(a1, pv[i], r1 * y);
    dg[i] = dgainf_(y);
    e2 = fmaf(a2, dg[i], r2 * e2);
  }

  // ---- EMA2 scan across the merged region
  float m2 = pow16f_(r2), b2 = e2;
  if (ch == 0 && tid == ETH - 1) { m2 = 0.0f; b2 = dgainf_(p0); }
  affine_scan<NW>(m2, b2, Mex, Bex, ssm);

  float st0 = 0.f, sq0 = 0.f, st1 = 0.f, sq1 = 0.f;
  if (tid >= ETH) {
    float g = Bex;
    float gv[PT];
#pragma unroll
    for (int i = 0; i < PT; ++i) { g = fmaf(a2, dg[i], r2 * g); gv[i] = g; }
    float* prow = pg + (size_t)b * Tt + tc + (tid - ETH) * PT;
#pragma unroll
    for (int i = 0; i < PT; i += 4)
      *(float4*)(prow + i) = make_float4(gv[i], gv[i + 1], gv[i + 2], gv[i + 3]);
#pragma unroll
    for (int i = 0; i < PT; ++i) {
      float u0 = xa[i] * gv[i]; st0 += u0; sq0 = fmaf(u0, u0, sq0);
      float u1 = xb[i] * gv[i]; st1 += u1; sq1 = fmaf(u1, u1, sq1);
    }
  }
  // block stats reduce -> partials[blockIdx.x]
#pragma unroll
  for (int d = 32; d > 0; d >>= 1) {
    st0 += __shfl_down(st0, d); sq0 += __shfl_down(sq0, d);
    st1 += __shfl_down(st1, d); sq1 += __shfl_down(sq1, d);
  }
  const int lane = tid & 63, wave = tid >> 6;
  if (lane == 0) { red[wave][0] = st0; red[wave][1] = sq0; red[wave][2] = st1; red[wave][3] = sq1; }
  __syncthreads();
  if (tid == 0) {
    float rs0 = 0, rq0 = 0, rs1 = 0, rq1 = 0;
#pragma unroll
    for (int wv = 0; wv < NW; ++wv) {
      rs0 += red[wv][0]; rq0 += red[wv][1]; rs1 += red[wv][2]; rq1 += red[wv][3];
    }
    float* pp = partials + (size_t)blockIdx.x * 4;
    pp[0] = rs0; pp[1] = rq0; pp[2] = rs1; pp[3] = rq1;
  }
}

// kB: per-row stats finalize + out = sA*x*g + off (NCB=32 partials per row).
__global__ __launch_bounds__(256) void k_out(
    const float* __restrict__ x, const float* __restrict__ gain,
    const float* __restrict__ partials,
    const float* __restrict__ dc_w, const float* __restrict__ gamma,
    const float* __restrict__ beta, float* __restrict__ out) {
  __shared__ float stm[4];
  const int b = blockIdx.x >> 7;   // 128 blocks per batch row
  const int tid = threadIdx.x;
  float s0 = 0.f, q0 = 0.f, s1 = 0.f, q1 = 0.f;
  if (tid < NCB) {
    const float* pp = partials + (size_t)(b * NCB + tid) * 4;
    s0 = pp[0]; q0 = pp[1]; s1 = pp[2]; q1 = pp[3];
  }
#pragma unroll
  for (int d = 16; d > 0; d >>= 1) {
    s0 += __shfl_down(s0, d); q0 += __shfl_down(q0, d);
    s1 += __shfl_down(s1, d); q1 += __shfl_down(q1, d);
  }
  if (tid == 0) {
    const float m0 = s0 / (float)Tt, m1 = s1 / (float)Tt;
    const float v0 = q0 / (float)Tt - m0 * m0;
    const float v1 = q1 / (float)Tt - m1 * m1;
    const float dw0 = dc_w[0], dw1 = dc_w[1];
    const float sA0 = gamma[0] * dw0 / sqrtf(fmaf(dw0 * dw0, v0, 1e-5f));
    const float sA1 = gamma[1] * dw1 / sqrtf(fmaf(dw1 * dw1, v1, 1e-5f));
    stm[0] = sA0; stm[1] = beta[0] - sA0 * m0;   // dc_b cancels in layernorm
    stm[2] = sA1; stm[3] = beta[1] - sA1 * m1;
  }
  __syncthreads();
  const float sA0 = stm[0], off0 = stm[1], sA1 = stm[2], off1 = stm[3];
  const int t = (((blockIdx.x & 127) << 8) + tid) << 2;
  const float4 g = *(const float4*)(gain + (size_t)b * Tt + t);
  {
    const size_t o = (size_t)(b * 2 + 0) * Tt + t;
    const float4 xv = *(const float4*)(x + o);
    float4 ov;
    ov.x = fmaf(sA0 * g.x, xv.x, off0);
    ov.y = fmaf(sA0 * g.y, xv.y, off0);
    ov.z = fmaf(sA0 * g.z, xv.z, off0);
    ov.w = fmaf(sA0 * g.w, xv.w, off0);
    *(float4*)(out + o) = ov;
  }
  {
    const size_t o = (size_t)(b * 2 + 1) * Tt + t;
    const float4 xv = *(const float4*)(x + o);
    float4 ov;
    ov.x = fmaf(sA1 * g.x, xv.x, off1);
    ov.y = fmaf(sA1 * g.y, xv.y, off1);
    ov.z = fmaf(sA1 * g.z, xv.z, off1);
    ov.w = fmaf(sA1 * g.w, xv.w, off1);
    *(float4*)(out + o) = ov;
  }
}

extern "C" void kernel_launch(void* const* d_in, const int* in_sizes, int n_in,
                              void* d_out, int out_size, void* d_ws, size_t ws_size,
                              hipStream_t stream) {
  const float* x         = (const float*)d_in[0];
  const float* conv_w    = (const float*)d_in[1];
  const float* combine_w = (const float*)d_in[2];
  const float* combine_b = (const float*)d_in[3];
  const float* la_att    = (const float*)d_in[4];
  const float* la_rel    = (const float*)d_in[5];
  const float* dc_w      = (const float*)d_in[6];
  const float* gamma     = (const float*)d_in[8];
  const float* beta      = (const float*)d_in[9];
  float* out = (float*)d_out;
  float* ws = (float*)d_ws;

  float* pg       = ws;                    // Bb*Tt floats: gain
  float* partials = ws + (size_t)Bb * Tt;  // Bb*NCB*4

  hipLaunchKernelGGL(k_gain, dim3(Bb * NCB), dim3(TPB), 0, stream,
                     x, conv_w, combine_w, combine_b, la_att, la_rel, pg, partials);
  hipLaunchKernelGGL(k_out, dim3(Bb * 128), dim3(256), 0, stream,
                     x, pg, partials, dc_w, gamma, beta, out);
}